// Round 8
// baseline (115.604 us; speedup 1.0000x reference)
//
#include <hip/hip_runtime.h>
#include <hip/hip_bf16.h>

#define CH 64      // channels
#define NN 4096    // h*w
#define NB 4       // batch
#define SPLIT 8
#define KLEN (NN / SPLIT)   // 512 keys per split, staged once per block
#define VSTRIDE 520         // u16 per V row in LDS (1040B: 16B-aligned, bank-skewed)
#define LOG2E 1.44269504f

typedef unsigned short u16;
typedef unsigned int u32;
typedef __attribute__((ext_vector_type(8))) short bf16x8;
typedef __attribute__((ext_vector_type(16))) float f32x16;

// f32 -> bf16 (RNE), scalar
static __device__ __forceinline__ u16 bf16r(float f) {
  union { float f; unsigned u; } v; v.f = f;
  unsigned x = v.u;
  x += 0x7fffu + ((x >> 16) & 1u);
  return (u16)(x >> 16);
}
// pack two f32 -> u32 of two bf16 via v_cvt_pk_bf16_f32 (RNE)
static __device__ __forceinline__ u32 pkc(float a, float b) {
  union { __hip_bfloat162 h; u32 u; } r;
  r.h = __float22bfloat162_rn(float2{a, b});
  return r.u;
}

// ---------------- Kernel 0: build W' A-frag table once ---------------------
// W' = [wv; wq; wk; 0] (96x64). Entry (t,s,l): W'[32t+(l&31)][16s+8(l>>5)+j],
// j=0..8, packed bf16. 768 entries x 16B = 12KB, written to ws.
__global__ __launch_bounds__(192) void prep_w(
    const float* __restrict__ wq, const float* __restrict__ wk,
    const float* __restrict__ wv, u16* __restrict__ Afr) {
  for (int idx = threadIdx.x; idx < 768; idx += 192) {
    const int l = idx & 63;
    const int s = (idx >> 6) & 3;
    const int t = idx >> 8;
    const int row = 32 * t + (l & 31);
    const int c0 = 16 * s + 8 * (l >> 5);
    float e[8];
#pragma unroll
    for (int j = 0; j < 8; ++j) {
      float v = 0.f;
      if (row < 64)      v = wv[row * 64 + c0 + j];
      else if (row < 72) v = wq[(row - 64) * 64 + c0 + j];
      else if (row < 80) v = wk[(row - 72) * 64 + c0 + j];
      e[j] = v;
    }
    u32* dst = reinterpret_cast<u32*>(Afr + (size_t)idx * 8);
    dst[0] = pkc(e[0], e[1]); dst[1] = pkc(e[2], e[3]);
    dst[2] = pkc(e[4], e[5]); dst[3] = pkc(e[6], e[7]);
  }
}

// ---------------- Kernel A: QKV projection (t-split waves) -----------------
// 512 blocks x 192 thr; block = one 32-position tile; wave t in {0,1,2} owns
// output row-tile t of W'. A-frags read coalesced from the prebuilt table
// (4x 16B per lane). x staged once to LDS via float4. V stored with keys
// bit-2<->3 swapped within each 32-group; Q pre-scaled by log2(e).
__global__ __launch_bounds__(192) void qkv_proj(
    const float* __restrict__ x, const u16* __restrict__ Afr,
    const float* __restrict__ bq, const float* __restrict__ bk,
    const float* __restrict__ bv,
    u16* __restrict__ Qb, u16* __restrict__ Kb, u16* __restrict__ Vb) {
  __shared__ float xs[64 * 32];            // [ch][pos] 8 KB
  const int tid = threadIdx.x;
  const int b = blockIdx.x >> 7;
  const int n0 = (blockIdx.x & 127) << 5;

  const float* xbase = x + (size_t)b * CH * NN + n0;
  for (int i = tid; i < 512; i += 192) {   // 64 rows x 8 float4
    const int row = i >> 3, c4 = i & 7;
    *reinterpret_cast<float4*>(&xs[row * 32 + c4 * 4]) =
        *reinterpret_cast<const float4*>(xbase + (size_t)row * NN + c4 * 4);
  }
  __syncthreads();

  const int w = __builtin_amdgcn_readfirstlane(tid >> 6);   // row-tile t
  const int lane = tid & 63;
  const int l31 = lane & 31;
  const int h = lane >> 5;
  const int n = n0 + l31;

  f32x16 acc = {};
#pragma unroll
  for (int s = 0; s < 4; ++s) {
    const bf16x8 af = *reinterpret_cast<const bf16x8*>(
        Afr + ((size_t)(w * 4 + s) * 64 + lane) * 8);
    float xv[8];
#pragma unroll
    for (int j = 0; j < 8; ++j)
      xv[j] = xs[(16 * s + 8 * h + j) * 32 + l31];
    union { uint4 u; bf16x8 v; } bf;
    bf.u.x = pkc(xv[0], xv[1]); bf.u.y = pkc(xv[2], xv[3]);
    bf.u.z = pkc(xv[4], xv[5]); bf.u.w = pkc(xv[6], xv[7]);
    acc = __builtin_amdgcn_mfma_f32_32x32x16_bf16(af, bf.v, acc, 0, 0, 0);
  }

  if (w < 2) {
    // V rows [32w, 32w+32); permuted n store (bit2<->3 swap within 32-group)
    const int sperm = (l31 & 19) | ((l31 & 4) << 1) | ((l31 & 8) >> 1);
    const int nperm = n0 + sperm;
#pragma unroll
    for (int r = 0; r < 16; ++r) {
      const int row = 32 * w + (r & 3) + 8 * (r >> 2) + 4 * h;
      Vb[((size_t)b * CH + row) * NN + nperm] = bf16r(acc[r] + bv[row]);
    }
  } else {
    // regs 0-3 = Q rows 4h..4h+3 ; regs 4-7 = K rows 4h..4h+3 (rest pad)
    const float q0 = (acc[0] + bq[4 * h + 0]) * LOG2E;
    const float q1 = (acc[1] + bq[4 * h + 1]) * LOG2E;
    const float q2 = (acc[2] + bq[4 * h + 2]) * LOG2E;
    const float q3 = (acc[3] + bq[4 * h + 3]) * LOG2E;
    const float k0 = acc[4] + bk[4 * h + 0];
    const float k1 = acc[5] + bk[4 * h + 1];
    const float k2 = acc[6] + bk[4 * h + 2];
    const float k3 = acc[7] + bk[4 * h + 3];
    uint2 qv, kv;
    qv.x = pkc(q0, q1); qv.y = pkc(q2, q3);
    kv.x = pkc(k0, k1); kv.y = pkc(k2, k3);
    *reinterpret_cast<uint2*>(Qb + ((size_t)b * NN + n) * 8 + 4 * h) = qv;
    *reinterpret_cast<uint2*>(Kb + ((size_t)b * NN + n) * 8 + 4 * h) = kv;
  }
}

// ---------------- Kernel B: persistent-slice flash attention ---------------
// 256 blocks (4b x 8qc x 8sp) x 1024 thr (16 waves x 32 q-rows). Full K/V
// slice staged ONCE (K 8.2KB + V 66.6KB, bank-skewed + XOR chunk swizzle),
// then 16 barrier-free key-iterations. QK = one 32x32x16 MFMA (d=8 zero-
// padded); P in registers (cvt_pk packs); PV = 4 MFMAs; l computed by a
// 3rd "ones-channel" accumulator on the matrix pipe (no VALU sum).
__global__ __launch_bounds__(1024, 4) void flash_attn(
    const u16* __restrict__ Qb, const u16* __restrict__ Kb,
    const u16* __restrict__ Vb, u32* __restrict__ ACCu,
    float* __restrict__ Lb) {
  __shared__ u16 Klds[KLEN * 8 + 8];       // + 16B zero pad for h1 reads
  __shared__ u16 Vlds[64 * VSTRIDE];
  const int bid = blockIdx.x;
  const int sp = bid & 7;                  // one split per XCD (round-robin)
  const int rest = bid >> 3;               // 0..31
  const int qc = rest & 7;
  const int b = rest >> 3;
  const int w = __builtin_amdgcn_readfirstlane(threadIdx.x >> 6);
  const int lane = threadIdx.x & 63;
  const int l31 = lane & 31;
  const int h = lane >> 5;
  const int qrow0 = qc * 512 + w * 32;
  const int ks = sp * KLEN;

  if (threadIdx.x < 8) Klds[KLEN * 8 + threadIdx.x] = 0;

  bf16x8 qf = {0, 0, 0, 0, 0, 0, 0, 0};
  if (h == 0)
    qf = *reinterpret_cast<const bf16x8*>(Qb + ((size_t)b * NN + qrow0 + l31) * 8);

  const u16* Kp = Kb + ((size_t)b * NN + ks) * 8;
  const u16* Vp = Vb + (size_t)b * CH * NN + ks;

  // stage once: wave w stages V rows 4w..4w+3; waves 0-7 stage K.
  // Global source chunk pre-swizzled with mask m(ch) = (ch ^ (ch>>3)) & 7;
  // LDS dest linear (involution applied again on read).
#pragma unroll
  for (int i = 0; i < 4; ++i) {
    const int ch = 4 * w + i;
    const int m = (ch ^ (ch >> 3)) & 7;
    const u16* src = Vp + (size_t)ch * NN + (((lane & 56) | ((lane ^ m) & 7)) << 3);
    __builtin_amdgcn_global_load_lds(
        (const __attribute__((address_space(1))) void*)src,
        (__attribute__((address_space(3))) void*)&Vlds[ch * VSTRIDE], 16, 0, 0);
  }
  if (w < 8)
    __builtin_amdgcn_global_load_lds(
        (const __attribute__((address_space(1))) void*)(Kp + ((size_t)(64 * w + lane)) * 8),
        (__attribute__((address_space(3))) void*)&Klds[64 * w * 8], 16, 0, 0);
  __syncthreads();                         // drains staging; the only barrier

  f32x16 acc0 = {}, acc1 = {}, acc2 = {};
  const f32x16 zz = {};
  const short one = (short)0x3F80;         // bf16 1.0
  const bf16x8 zero8 = {0, 0, 0, 0, 0, 0, 0, 0};
  const bf16x8 ones8 = {one, one, one, one, one, one, one, one};
  const bf16x8 af1 = (l31 == 0) ? ones8 : zero8;  // ones-channel A-frag (row 0)
  const int m0 = (l31 ^ (l31 >> 3)) & 7;   // swizzle mask for ch = l31
  const int m1 = m0 ^ 4;                   // for ch = 32 + l31

#pragma unroll 4
  for (int kk = 0; kk < KLEN / 32; ++kk) {
    // QK: A = K[32 keys][d] (h1 -> zero pad), B = Q^T (h1 -> zeros)
    const int kaddr = h ? KLEN * 8 : (kk * 32 + l31) * 8;
    bf16x8 kf = *reinterpret_cast<const bf16x8*>(Klds + kaddr);
    f32x16 s = __builtin_amdgcn_mfma_f32_32x32x16_bf16(kf, qf, zz, 0, 0, 0);
    // P = exp2(S); lane (q=l31, h) holds key perm-slots (r&3)+8*(r>>2)+4h
    float p[16];
#pragma unroll
    for (int r = 0; r < 16; ++r) p[r] = exp2f(s[r]);
    union { uint4 u; bf16x8 v; } pb0, pb1;
    pb0.u.x = pkc(p[0], p[1]);   pb0.u.y = pkc(p[2], p[3]);
    pb0.u.z = pkc(p[4], p[5]);   pb0.u.w = pkc(p[6], p[7]);
    pb1.u.x = pkc(p[8], p[9]);   pb1.u.y = pkc(p[10], p[11]);
    pb1.u.z = pkc(p[12], p[13]); pb1.u.w = pkc(p[14], p[15]);
    // PV: O^T[64ch][32q]; 16B chunk g deswizzled per-row
    const int g0 = kk * 4 + h;
    const int g1 = g0 + 2;
    const int cp00 = (g0 & 56) | ((g0 ^ m0) & 7);
    const int cp01 = (g1 & 56) | ((g1 ^ m0) & 7);
    const int cp10 = (g0 & 56) | ((g0 ^ m1) & 7);
    const int cp11 = (g1 & 56) | ((g1 ^ m1) & 7);
    bf16x8 v00 = *reinterpret_cast<const bf16x8*>(Vlds + l31 * VSTRIDE + cp00 * 8);
    bf16x8 v01 = *reinterpret_cast<const bf16x8*>(Vlds + l31 * VSTRIDE + cp01 * 8);
    bf16x8 v10 = *reinterpret_cast<const bf16x8*>(Vlds + (32 + l31) * VSTRIDE + cp10 * 8);
    bf16x8 v11 = *reinterpret_cast<const bf16x8*>(Vlds + (32 + l31) * VSTRIDE + cp11 * 8);
    acc0 = __builtin_amdgcn_mfma_f32_32x32x16_bf16(v00, pb0.v, acc0, 0, 0, 0);
    acc0 = __builtin_amdgcn_mfma_f32_32x32x16_bf16(v01, pb1.v, acc0, 0, 0, 0);
    acc1 = __builtin_amdgcn_mfma_f32_32x32x16_bf16(v10, pb0.v, acc1, 0, 0, 0);
    acc1 = __builtin_amdgcn_mfma_f32_32x32x16_bf16(v11, pb1.v, acc1, 0, 0, 0);
    acc2 = __builtin_amdgcn_mfma_f32_32x32x16_bf16(af1, pb0.v, acc2, 0, 0, 0);
    acc2 = __builtin_amdgcn_mfma_f32_32x32x16_bf16(af1, pb1.v, acc2, 0, 0, 0);
  }

  // l(q) = acc2 row 0 (lives on h=0 lanes, reg 0); h=1 half holds 0.
  float lsum = acc2[0];
  lsum += __shfl_xor(lsum, 32);            // replicate across h

  // partials: ACC as packed bf16 ch-pairs [gtile][sp][32 chpair][32 q]
  const int gtile = b * (NN / 32) + qc * 16 + w;
  u32* A = ACCu + ((size_t)gtile * SPLIT + sp) * 32 * 32;
#pragma unroll
  for (int rp = 0; rp < 8; ++rp) {
    const int chp = (rp & 1) + 4 * (rp >> 1) + 2 * h;   // = ch>>1, ch even
    __builtin_nontemporal_store(pkc(acc0[2 * rp], acc0[2 * rp + 1]),
                                &A[chp * 32 + l31]);
    __builtin_nontemporal_store(pkc(acc1[2 * rp], acc1[2 * rp + 1]),
                                &A[(16 + chp) * 32 + l31]);
  }
  if (h == 0)
    __builtin_nontemporal_store(lsum, &Lb[((size_t)gtile * SPLIT + sp) * 32 + l31]);
}

// ---------------- Kernel C: combine split partials + epilogue ---------------
// One thread -> 4 consecutive positions x 2 channels (vectorized).
__global__ __launch_bounds__(256) void combine(
    const float* __restrict__ x, const float* __restrict__ gamma,
    const u32* __restrict__ ACCu, const float* __restrict__ Lb,
    float* __restrict__ out) {
  const int idx = blockIdx.x * 256 + threadIdx.x;   // over NB*32*(NN/4)
  const int n4 = idx & (NN / 4 - 1);
  const int cp = (idx >> 10) & 31;
  const int b = idx >> 15;
  const int n = n4 << 2;
  const int gtile = b * (NN / 32) + (n >> 5);
  const int q0 = n & 31;                   // multiple of 4
  const uint4* A4 = reinterpret_cast<const uint4*>(ACCu);
  const float4* L4 = reinterpret_cast<const float4*>(Lb);
  float s0[4] = {0.f, 0.f, 0.f, 0.f}, s1[4] = {0.f, 0.f, 0.f, 0.f};
  float l[4] = {0.f, 0.f, 0.f, 0.f};
#pragma unroll
  for (int sp = 0; sp < SPLIT; ++sp) {
    const uint4 a = A4[(((size_t)gtile * SPLIT + sp) * 32 + cp) * 8 + (q0 >> 2)];
    const float4 lv = L4[(((size_t)gtile * SPLIT + sp) * 32 + q0) >> 2];
    const u32 av[4] = {a.x, a.y, a.z, a.w};
#pragma unroll
    for (int k = 0; k < 4; ++k) {
      union { u32 u; float f; } lo, hi;
      lo.u = av[k] << 16; hi.u = av[k] & 0xffff0000u;
      s0[k] += lo.f; s1[k] += hi.f;
    }
    l[0] += lv.x; l[1] += lv.y; l[2] += lv.z; l[3] += lv.w;
  }
  const float gm = gamma[0];
  float inv[4];
#pragma unroll
  for (int k = 0; k < 4; ++k) inv[k] = gm / l[k];
  const size_t i0 = ((size_t)b * CH + 2 * cp) * NN + n;
  const float4 x0 = *reinterpret_cast<const float4*>(x + i0);
  const float4 x1 = *reinterpret_cast<const float4*>(x + i0 + NN);
  float4 o0, o1;
  o0.x = fmaf(inv[0], s0[0], x0.x); o0.y = fmaf(inv[1], s0[1], x0.y);
  o0.z = fmaf(inv[2], s0[2], x0.z); o0.w = fmaf(inv[3], s0[3], x0.w);
  o1.x = fmaf(inv[0], s1[0], x1.x); o1.y = fmaf(inv[1], s1[1], x1.y);
  o1.z = fmaf(inv[2], s1[2], x1.z); o1.w = fmaf(inv[3], s1[3], x1.w);
  *reinterpret_cast<float4*>(out + i0) = o0;
  *reinterpret_cast<float4*>(out + i0 + NN) = o1;
}

extern "C" void kernel_launch(void* const* d_in, const int* in_sizes, int n_in,
                              void* d_out, int out_size, void* d_ws, size_t ws_size,
                              hipStream_t stream) {
  const float* x     = (const float*)d_in[0];
  const float* wq    = (const float*)d_in[1];
  const float* bq    = (const float*)d_in[2];
  const float* wk    = (const float*)d_in[3];
  const float* bk    = (const float*)d_in[4];
  const float* wv    = (const float*)d_in[5];
  const float* bv    = (const float*)d_in[6];
  const float* gamma = (const float*)d_in[7];
  float* out = (float*)d_out;

  // ws: Q 256KB | K 256KB | V 2MB | ACC(bf16 pairs) 16MB | L 512KB | Afr 12KB
  u16* Qb = (u16*)d_ws;
  u16* Kb = Qb + (size_t)NB * NN * 8;
  u16* Vb = Kb + (size_t)NB * NN * 8;
  u32* ACCu = (u32*)(Vb + (size_t)NB * CH * NN);
  float* Lb = (float*)(ACCu + (size_t)NB * (NN / 32) * SPLIT * 32 * 32);
  u16* Afr = (u16*)(Lb + (size_t)NB * (NN / 32) * SPLIT * 32);

  prep_w<<<dim3(1), dim3(192), 0, stream>>>(wq, wk, wv, Afr);
  qkv_proj<<<dim3(NB * (NN / 32)), dim3(192), 0, stream>>>(
      x, Afr, bq, bk, bv, Qb, Kb, Vb);
  flash_attn<<<dim3(NB * 8 * SPLIT), dim3(1024), 0, stream>>>(
      Qb, Kb, Vb, ACCu, Lb);
  combine<<<dim3((NB * 32 * (NN / 4)) / 256), dim3(256), 0, stream>>>(
      x, gamma, ACCu, Lb, out);
}

// Round 9
// 112.354 us; speedup vs baseline: 1.0289x; 1.0289x over previous
//
#include <hip/hip_runtime.h>
#include <hip/hip_bf16.h>

#define CH 64      // channels
#define NN 4096    // h*w
#define NB 4       // batch
#define SPLIT 4
#define KLEN (NN / SPLIT)   // 1024 keys per split, staged in 2 phases of 512
#define PHK 512             // keys per staging phase
#define VSTRIDE 520         // u16 per V row in LDS (1040B: 16B-aligned, bank-skewed)
#define LOG2E 1.44269504f

typedef unsigned short u16;
typedef unsigned int u32;
typedef __attribute__((ext_vector_type(8))) short bf16x8;
typedef __attribute__((ext_vector_type(16))) float f32x16;

// f32 -> bf16 (RNE), scalar
static __device__ __forceinline__ u16 bf16r(float f) {
  union { float f; unsigned u; } v; v.f = f;
  unsigned x = v.u;
  x += 0x7fffu + ((x >> 16) & 1u);
  return (u16)(x >> 16);
}
// pack two f32 -> u32 of two bf16 via v_cvt_pk_bf16_f32 (RNE)
static __device__ __forceinline__ u32 pkc(float a, float b) {
  union { __hip_bfloat162 h; u32 u; } r;
  r.h = __float22bfloat162_rn(float2{a, b});
  return r.u;
}

// ---------------- Kernel 0: build W' A-frag table once ---------------------
// W' = [wv; wq; wk; 0] (96x64). Entry (t,s,l): W'[32t+(l&31)][16s+8(l>>5)+j],
// j=0..8, packed bf16. 768 entries x 16B = 12KB, written to ws.
__global__ __launch_bounds__(192) void prep_w(
    const float* __restrict__ wq, const float* __restrict__ wk,
    const float* __restrict__ wv, u16* __restrict__ Afr) {
  for (int idx = threadIdx.x; idx < 768; idx += 192) {
    const int l = idx & 63;
    const int s = (idx >> 6) & 3;
    const int t = idx >> 8;
    const int row = 32 * t + (l & 31);
    const int c0 = 16 * s + 8 * (l >> 5);
    float e[8];
#pragma unroll
    for (int j = 0; j < 8; ++j) {
      float v = 0.f;
      if (row < 64)      v = wv[row * 64 + c0 + j];
      else if (row < 72) v = wq[(row - 64) * 64 + c0 + j];
      else if (row < 80) v = wk[(row - 72) * 64 + c0 + j];
      e[j] = v;
    }
    u32* dst = reinterpret_cast<u32*>(Afr + (size_t)idx * 8);
    dst[0] = pkc(e[0], e[1]); dst[1] = pkc(e[2], e[3]);
    dst[2] = pkc(e[4], e[5]); dst[3] = pkc(e[6], e[7]);
  }
}

// ---------------- Kernel A: QKV projection (t-split waves) -----------------
// 512 blocks x 192 thr; block = one 32-position tile; wave t in {0,1,2} owns
// output row-tile t of W'. A-frags read coalesced from the prebuilt table.
// x staged once to LDS via float4. V stored with keys bit-2<->3 swapped
// within each 32-group; Q pre-scaled by log2(e).
__global__ __launch_bounds__(192) void qkv_proj(
    const float* __restrict__ x, const u16* __restrict__ Afr,
    const float* __restrict__ bq, const float* __restrict__ bk,
    const float* __restrict__ bv,
    u16* __restrict__ Qb, u16* __restrict__ Kb, u16* __restrict__ Vb) {
  __shared__ float xs[64 * 32];            // [ch][pos] 8 KB
  const int tid = threadIdx.x;
  const int b = blockIdx.x >> 7;
  const int n0 = (blockIdx.x & 127) << 5;

  const float* xbase = x + (size_t)b * CH * NN + n0;
  for (int i = tid; i < 512; i += 192) {   // 64 rows x 8 float4
    const int row = i >> 3, c4 = i & 7;
    *reinterpret_cast<float4*>(&xs[row * 32 + c4 * 4]) =
        *reinterpret_cast<const float4*>(xbase + (size_t)row * NN + c4 * 4);
  }
  __syncthreads();

  const int w = __builtin_amdgcn_readfirstlane(tid >> 6);   // row-tile t
  const int lane = tid & 63;
  const int l31 = lane & 31;
  const int h = lane >> 5;
  const int n = n0 + l31;

  f32x16 acc = {};
#pragma unroll
  for (int s = 0; s < 4; ++s) {
    const bf16x8 af = *reinterpret_cast<const bf16x8*>(
        Afr + ((size_t)(w * 4 + s) * 64 + lane) * 8);
    float xv[8];
#pragma unroll
    for (int j = 0; j < 8; ++j)
      xv[j] = xs[(16 * s + 8 * h + j) * 32 + l31];
    union { uint4 u; bf16x8 v; } bf;
    bf.u.x = pkc(xv[0], xv[1]); bf.u.y = pkc(xv[2], xv[3]);
    bf.u.z = pkc(xv[4], xv[5]); bf.u.w = pkc(xv[6], xv[7]);
    acc = __builtin_amdgcn_mfma_f32_32x32x16_bf16(af, bf.v, acc, 0, 0, 0);
  }

  if (w < 2) {
    // V rows [32w, 32w+32); permuted n store (bit2<->3 swap within 32-group)
    const int sperm = (l31 & 19) | ((l31 & 4) << 1) | ((l31 & 8) >> 1);
    const int nperm = n0 + sperm;
#pragma unroll
    for (int r = 0; r < 16; ++r) {
      const int row = 32 * w + (r & 3) + 8 * (r >> 2) + 4 * h;
      Vb[((size_t)b * CH + row) * NN + nperm] = bf16r(acc[r] + bv[row]);
    }
  } else {
    // regs 0-3 = Q rows 4h..4h+3 ; regs 4-7 = K rows 4h..4h+3 (rest pad)
    const float q0 = (acc[0] + bq[4 * h + 0]) * LOG2E;
    const float q1 = (acc[1] + bq[4 * h + 1]) * LOG2E;
    const float q2 = (acc[2] + bq[4 * h + 2]) * LOG2E;
    const float q3 = (acc[3] + bq[4 * h + 3]) * LOG2E;
    const float k0 = acc[4] + bk[4 * h + 0];
    const float k1 = acc[5] + bk[4 * h + 1];
    const float k2 = acc[6] + bk[4 * h + 2];
    const float k3 = acc[7] + bk[4 * h + 3];
    uint2 qv, kv;
    qv.x = pkc(q0, q1); qv.y = pkc(q2, q3);
    kv.x = pkc(k0, k1); kv.y = pkc(k2, k3);
    *reinterpret_cast<uint2*>(Qb + ((size_t)b * NN + n) * 8 + 4 * h) = qv;
    *reinterpret_cast<uint2*>(Kb + ((size_t)b * NN + n) * 8 + 4 * h) = kv;
  }
}

// ---------------- Kernel B: two-phase persistent flash attention -----------
// SPLIT=4: 256 blocks (4b x 16qc x 4sp) x 512 thr (8 waves x 32 q-rows);
// 2 blocks/CU (LDS 74.8KB) so one block computes while the other stages.
// sp = bid&3 is XCD-constant (bid&7 fixed per XCD), so the 16 co-resident
// qc-blocks of a (b,sp) slice share L2. Each block's 1024-key slice is
// staged in 2 phases of 512 keys (K 8.2KB + V 66.6KB, bank-skewed + XOR
// chunk swizzle). QK = one 32x32x16 MFMA (d=8 zero-padded); P in registers;
// PV = 4 MFMAs; l via a "ones-channel" MFMA accumulator. ACC halves vs
// SPLIT=8 (8.4MB) -> less HBM traffic + poison-eviction drag.
__global__ __launch_bounds__(512, 4) void flash_attn(
    const u16* __restrict__ Qb, const u16* __restrict__ Kb,
    const u16* __restrict__ Vb, u32* __restrict__ ACCu,
    float* __restrict__ Lb) {
  __shared__ u16 Klds[PHK * 8 + 8];        // + 16B zero pad for h1 reads
  __shared__ u16 Vlds[64 * VSTRIDE];
  const int bid = blockIdx.x;
  const int sp = bid & 3;                  // XCD-constant
  const int rest = bid >> 2;               // 0..63
  const int qc = rest & 15;
  const int b = rest >> 4;
  const int w = __builtin_amdgcn_readfirstlane(threadIdx.x >> 6);
  const int lane = threadIdx.x & 63;
  const int l31 = lane & 31;
  const int h = lane >> 5;
  const int qrow0 = qc * 256 + w * 32;
  const int ks = sp * KLEN;

  if (threadIdx.x < 8) Klds[PHK * 8 + threadIdx.x] = 0;

  bf16x8 qf = {0, 0, 0, 0, 0, 0, 0, 0};
  if (h == 0)
    qf = *reinterpret_cast<const bf16x8*>(Qb + ((size_t)b * NN + qrow0 + l31) * 8);

  const u16* Kp = Kb + ((size_t)b * NN + ks) * 8;
  const u16* Vp = Vb + (size_t)b * CH * NN + ks;

  f32x16 acc0 = {}, acc1 = {}, acc2 = {};
  const f32x16 zz = {};
  const short one = (short)0x3F80;         // bf16 1.0
  const bf16x8 zero8 = {0, 0, 0, 0, 0, 0, 0, 0};
  const bf16x8 ones8 = {one, one, one, one, one, one, one, one};
  const bf16x8 af1 = (l31 == 0) ? ones8 : zero8;  // ones-channel A-frag
  const int m0 = (l31 ^ (l31 >> 3)) & 7;   // swizzle mask for ch = l31
  const int m1 = m0 ^ 4;                   // for ch = 32 + l31

  // stage phase ph: wave w stages V rows 8w..8w+7 (1 instr/row, lane=chunk);
  // wave w stages K keys [64w, 64w+64). Global source chunk pre-swizzled
  // with mask m(ch) = (ch ^ (ch>>3)) & 7; LDS dest linear.
#define STAGE(ph) do {                                                        \
    _Pragma("unroll")                                                         \
    for (int i = 0; i < 8; ++i) {                                             \
      const int ch = 8 * w + i;                                               \
      const int mm = (ch ^ (ch >> 3)) & 7;                                    \
      const u16* src = Vp + (size_t)ch * NN + (ph) * PHK +                    \
                       (((lane & 56) | ((lane ^ mm) & 7)) << 3);              \
      __builtin_amdgcn_global_load_lds(                                       \
          (const __attribute__((address_space(1))) void*)src,                 \
          (__attribute__((address_space(3))) void*)&Vlds[ch * VSTRIDE], 16, 0, 0); \
    }                                                                         \
    __builtin_amdgcn_global_load_lds(                                         \
        (const __attribute__((address_space(1))) void*)(Kp + ((size_t)(ph) * PHK + 64 * w + lane) * 8), \
        (__attribute__((address_space(3))) void*)&Klds[64 * w * 8], 16, 0, 0); \
  } while (0)

#pragma unroll
  for (int ph = 0; ph < 2; ++ph) {
    STAGE(ph);
    __syncthreads();                       // staging drained; LDS ready
#pragma unroll 4
    for (int kk = 0; kk < PHK / 32; ++kk) {
      // QK: A = K[32 keys][d] (h1 -> zero pad), B = Q^T (h1 -> zeros)
      const int kaddr = h ? PHK * 8 : (kk * 32 + l31) * 8;
      bf16x8 kf = *reinterpret_cast<const bf16x8*>(Klds + kaddr);
      f32x16 s = __builtin_amdgcn_mfma_f32_32x32x16_bf16(kf, qf, zz, 0, 0, 0);
      // P = exp2(S); lane (q=l31, h) holds key perm-slots (r&3)+8*(r>>2)+4h
      float p[16];
#pragma unroll
      for (int r = 0; r < 16; ++r) p[r] = exp2f(s[r]);
      union { uint4 u; bf16x8 v; } pb0, pb1;
      pb0.u.x = pkc(p[0], p[1]);   pb0.u.y = pkc(p[2], p[3]);
      pb0.u.z = pkc(p[4], p[5]);   pb0.u.w = pkc(p[6], p[7]);
      pb1.u.x = pkc(p[8], p[9]);   pb1.u.y = pkc(p[10], p[11]);
      pb1.u.z = pkc(p[12], p[13]); pb1.u.w = pkc(p[14], p[15]);
      // PV: O^T[64ch][32q]; 16B chunk g deswizzled per-row
      const int g0 = kk * 4 + h;
      const int g1 = g0 + 2;
      const int cp00 = (g0 & 56) | ((g0 ^ m0) & 7);
      const int cp01 = (g1 & 56) | ((g1 ^ m0) & 7);
      const int cp10 = (g0 & 56) | ((g0 ^ m1) & 7);
      const int cp11 = (g1 & 56) | ((g1 ^ m1) & 7);
      bf16x8 v00 = *reinterpret_cast<const bf16x8*>(Vlds + l31 * VSTRIDE + cp00 * 8);
      bf16x8 v01 = *reinterpret_cast<const bf16x8*>(Vlds + l31 * VSTRIDE + cp01 * 8);
      bf16x8 v10 = *reinterpret_cast<const bf16x8*>(Vlds + (32 + l31) * VSTRIDE + cp10 * 8);
      bf16x8 v11 = *reinterpret_cast<const bf16x8*>(Vlds + (32 + l31) * VSTRIDE + cp11 * 8);
      acc0 = __builtin_amdgcn_mfma_f32_32x32x16_bf16(v00, pb0.v, acc0, 0, 0, 0);
      acc0 = __builtin_amdgcn_mfma_f32_32x32x16_bf16(v01, pb1.v, acc0, 0, 0, 0);
      acc1 = __builtin_amdgcn_mfma_f32_32x32x16_bf16(v10, pb0.v, acc1, 0, 0, 0);
      acc1 = __builtin_amdgcn_mfma_f32_32x32x16_bf16(v11, pb1.v, acc1, 0, 0, 0);
      acc2 = __builtin_amdgcn_mfma_f32_32x32x16_bf16(af1, pb0.v, acc2, 0, 0, 0);
      acc2 = __builtin_amdgcn_mfma_f32_32x32x16_bf16(af1, pb1.v, acc2, 0, 0, 0);
    }
    if (ph == 0) __syncthreads();          // compute done; allow re-stage
  }
#undef STAGE

  // l(q) = acc2 row 0 (on h=0 lanes); replicate across h
  float lsum = acc2[0];
  lsum += __shfl_xor(lsum, 32);

  // partials: ACC as packed bf16 ch-pairs [gtile][sp][32 chpair][32 q]
  const int gtile = b * (NN / 32) + qc * 8 + w;
  u32* A = ACCu + ((size_t)gtile * SPLIT + sp) * 32 * 32;
#pragma unroll
  for (int rp = 0; rp < 8; ++rp) {
    const int chp = (rp & 1) + 4 * (rp >> 1) + 2 * h;   // = ch>>1, ch even
    __builtin_nontemporal_store(pkc(acc0[2 * rp], acc0[2 * rp + 1]),
                                &A[chp * 32 + l31]);
    __builtin_nontemporal_store(pkc(acc1[2 * rp], acc1[2 * rp + 1]),
                                &A[(16 + chp) * 32 + l31]);
  }
  if (h == 0)
    __builtin_nontemporal_store(lsum, &Lb[((size_t)gtile * SPLIT + sp) * 32 + l31]);
}

// ---------------- Kernel C: combine split partials + epilogue ---------------
// One thread -> 4 consecutive positions x 2 channels (vectorized).
__global__ __launch_bounds__(256) void combine(
    const float* __restrict__ x, const float* __restrict__ gamma,
    const u32* __restrict__ ACCu, const float* __restrict__ Lb,
    float* __restrict__ out) {
  const int idx = blockIdx.x * 256 + threadIdx.x;   // over NB*32*(NN/4)
  const int n4 = idx & (NN / 4 - 1);
  const int cp = (idx >> 10) & 31;
  const int b = idx >> 15;
  const int n = n4 << 2;
  const int gtile = b * (NN / 32) + (n >> 5);
  const int q0 = n & 31;                   // multiple of 4
  const uint4* A4 = reinterpret_cast<const uint4*>(ACCu);
  const float4* L4 = reinterpret_cast<const float4*>(Lb);
  float s0[4] = {0.f, 0.f, 0.f, 0.f}, s1[4] = {0.f, 0.f, 0.f, 0.f};
  float l[4] = {0.f, 0.f, 0.f, 0.f};
#pragma unroll
  for (int sp = 0; sp < SPLIT; ++sp) {
    const uint4 a = A4[(((size_t)gtile * SPLIT + sp) * 32 + cp) * 8 + (q0 >> 2)];
    const float4 lv = L4[(((size_t)gtile * SPLIT + sp) * 32 + q0) >> 2];
    const u32 av[4] = {a.x, a.y, a.z, a.w};
#pragma unroll
    for (int k = 0; k < 4; ++k) {
      union { u32 u; float f; } lo, hi;
      lo.u = av[k] << 16; hi.u = av[k] & 0xffff0000u;
      s0[k] += lo.f; s1[k] += hi.f;
    }
    l[0] += lv.x; l[1] += lv.y; l[2] += lv.z; l[3] += lv.w;
  }
  const float gm = gamma[0];
  float inv[4];
#pragma unroll
  for (int k = 0; k < 4; ++k) inv[k] = gm / l[k];
  const size_t i0 = ((size_t)b * CH + 2 * cp) * NN + n;
  const float4 x0 = *reinterpret_cast<const float4*>(x + i0);
  const float4 x1 = *reinterpret_cast<const float4*>(x + i0 + NN);
  float4 o0, o1;
  o0.x = fmaf(inv[0], s0[0], x0.x); o0.y = fmaf(inv[1], s0[1], x0.y);
  o0.z = fmaf(inv[2], s0[2], x0.z); o0.w = fmaf(inv[3], s0[3], x0.w);
  o1.x = fmaf(inv[0], s1[0], x1.x); o1.y = fmaf(inv[1], s1[1], x1.y);
  o1.z = fmaf(inv[2], s1[2], x1.z); o1.w = fmaf(inv[3], s1[3], x1.w);
  *reinterpret_cast<float4*>(out + i0) = o0;
  *reinterpret_cast<float4*>(out + i0 + NN) = o1;
}

extern "C" void kernel_launch(void* const* d_in, const int* in_sizes, int n_in,
                              void* d_out, int out_size, void* d_ws, size_t ws_size,
                              hipStream_t stream) {
  const float* x     = (const float*)d_in[0];
  const float* wq    = (const float*)d_in[1];
  const float* bq    = (const float*)d_in[2];
  const float* wk    = (const float*)d_in[3];
  const float* bk    = (const float*)d_in[4];
  const float* wv    = (const float*)d_in[5];
  const float* bv    = (const float*)d_in[6];
  const float* gamma = (const float*)d_in[7];
  float* out = (float*)d_out;

  // ws: Q 256KB | K 256KB | V 2MB | ACC(bf16 pairs) 8.4MB | L 256KB | Afr 12KB
  u16* Qb = (u16*)d_ws;
  u16* Kb = Qb + (size_t)NB * NN * 8;
  u16* Vb = Kb + (size_t)NB * NN * 8;
  u32* ACCu = (u32*)(Vb + (size_t)NB * CH * NN);
  float* Lb = (float*)(ACCu + (size_t)NB * (NN / 32) * SPLIT * 32 * 32);
  u16* Afr = (u16*)(Lb + (size_t)NB * (NN / 32) * SPLIT * 32);

  prep_w<<<dim3(1), dim3(192), 0, stream>>>(wq, wk, wv, Afr);
  qkv_proj<<<dim3(NB * (NN / 32)), dim3(192), 0, stream>>>(
      x, Afr, bq, bk, bv, Qb, Kb, Vb);
  flash_attn<<<dim3(NB * 16 * SPLIT), dim3(512), 0, stream>>>(
      Qb, Kb, Vb, ACCu, Lb);
  combine<<<dim3((NB * 32 * (NN / 4)) / 256), dim3(256), 0, stream>>>(
      x, gamma, ACCu, Lb, out);
}

// Round 10
// 111.648 us; speedup vs baseline: 1.0354x; 1.0063x over previous
//
#include <hip/hip_runtime.h>
#include <hip/hip_bf16.h>

#define CH 64      // channels
#define NN 4096    // h*w
#define NB 4       // batch
#define SPLIT 4
#define KLEN (NN / SPLIT)   // 1024 keys per split
#define PHK 256             // keys per staging phase (double-buffered)
#define NP (KLEN / PHK)     // 4 phases
#define VST 256             // u16 per V row in LDS (512B exact)
#define LOG2E 1.44269504f

typedef unsigned short u16;
typedef unsigned int u32;
typedef __attribute__((ext_vector_type(8))) short bf16x8;
typedef __attribute__((ext_vector_type(16))) float f32x16;

// f32 -> bf16 (RNE), scalar
static __device__ __forceinline__ u16 bf16r(float f) {
  union { float f; unsigned u; } v; v.f = f;
  unsigned x = v.u;
  x += 0x7fffu + ((x >> 16) & 1u);
  return (u16)(x >> 16);
}
// pack two f32 -> u32 of two bf16 via v_cvt_pk_bf16_f32 (RNE)
static __device__ __forceinline__ u32 pkc(float a, float b) {
  union { __hip_bfloat162 h; u32 u; } r;
  r.h = __float22bfloat162_rn(float2{a, b});
  return r.u;
}

// ---------------- Kernel A: QKV projection (t-split waves) -----------------
// 512 blocks x 192 thr; block = one 32-position tile; wave t in {0,1,2} owns
// output row-tile t of W'=[wv;wq;wk;0] (96x64). A-frag table built in-block
// (perf-neutral vs prebuilt table, r8). x staged to LDS via float4.
// V stored with keys bit-2<->3 swapped within each 32-group; Q pre-scaled
// by log2(e).
__global__ __launch_bounds__(192) void qkv_proj(
    const float* __restrict__ x,
    const float* __restrict__ wq, const float* __restrict__ bq,
    const float* __restrict__ wk, const float* __restrict__ bk,
    const float* __restrict__ wv, const float* __restrict__ bv,
    u16* __restrict__ Qb, u16* __restrict__ Kb, u16* __restrict__ Vb) {
  __shared__ float xs[64 * 32];            // [ch][pos] 8 KB
  __shared__ u16 afr_lds[3][4][64][8];     // 12 KB A-frag table
  const int tid = threadIdx.x;
  const int b = blockIdx.x >> 7;
  const int n0 = (blockIdx.x & 127) << 5;

  const float* xbase = x + (size_t)b * CH * NN + n0;
  for (int i = tid; i < 512; i += 192) {   // 64 rows x 8 float4
    const int row = i >> 3, c4 = i & 7;
    *reinterpret_cast<float4*>(&xs[row * 32 + c4 * 4]) =
        *reinterpret_cast<const float4*>(xbase + (size_t)row * NN + c4 * 4);
  }
  for (int i = tid; i < 768; i += 192) {   // 4 iters: build A-frag table
    const int l = i & 63;
    const int s = (i >> 6) & 3;
    const int t = i >> 8;
    const int row = 32 * t + (l & 31);
    const int c0 = 16 * s + 8 * (l >> 5);
    float e[8];
#pragma unroll
    for (int j = 0; j < 8; ++j) {
      float v = 0.f;
      if (row < 64)      v = wv[row * 64 + c0 + j];
      else if (row < 72) v = wq[(row - 64) * 64 + c0 + j];
      else if (row < 80) v = wk[(row - 72) * 64 + c0 + j];
      e[j] = v;
    }
    u32* dst = reinterpret_cast<u32*>(&afr_lds[t][s][l][0]);
    dst[0] = pkc(e[0], e[1]); dst[1] = pkc(e[2], e[3]);
    dst[2] = pkc(e[4], e[5]); dst[3] = pkc(e[6], e[7]);
  }
  __syncthreads();

  const int w = __builtin_amdgcn_readfirstlane(tid >> 6);   // row-tile t
  const int lane = tid & 63;
  const int l31 = lane & 31;
  const int h = lane >> 5;
  const int n = n0 + l31;

  f32x16 acc = {};
#pragma unroll
  for (int s = 0; s < 4; ++s) {
    const bf16x8 af = *reinterpret_cast<const bf16x8*>(&afr_lds[w][s][lane][0]);
    float xv[8];
#pragma unroll
    for (int j = 0; j < 8; ++j)
      xv[j] = xs[(16 * s + 8 * h + j) * 32 + l31];
    union { uint4 u; bf16x8 v; } bf;
    bf.u.x = pkc(xv[0], xv[1]); bf.u.y = pkc(xv[2], xv[3]);
    bf.u.z = pkc(xv[4], xv[5]); bf.u.w = pkc(xv[6], xv[7]);
    acc = __builtin_amdgcn_mfma_f32_32x32x16_bf16(af, bf.v, acc, 0, 0, 0);
  }

  if (w < 2) {
    // V rows [32w, 32w+32); permuted n store (bit2<->3 swap within 32-group)
    const int sperm = (l31 & 19) | ((l31 & 4) << 1) | ((l31 & 8) >> 1);
    const int nperm = n0 + sperm;
#pragma unroll
    for (int r = 0; r < 16; ++r) {
      const int row = 32 * w + (r & 3) + 8 * (r >> 2) + 4 * h;
      Vb[((size_t)b * CH + row) * NN + nperm] = bf16r(acc[r] + bv[row]);
    }
  } else {
    // regs 0-3 = Q rows 4h..4h+3 ; regs 4-7 = K rows 4h..4h+3 (rest pad)
    const float q0 = (acc[0] + bq[4 * h + 0]) * LOG2E;
    const float q1 = (acc[1] + bq[4 * h + 1]) * LOG2E;
    const float q2 = (acc[2] + bq[4 * h + 2]) * LOG2E;
    const float q3 = (acc[3] + bq[4 * h + 3]) * LOG2E;
    const float k0 = acc[4] + bk[4 * h + 0];
    const float k1 = acc[5] + bk[4 * h + 1];
    const float k2 = acc[6] + bk[4 * h + 2];
    const float k3 = acc[7] + bk[4 * h + 3];
    uint2 qv, kv;
    qv.x = pkc(q0, q1); qv.y = pkc(q2, q3);
    kv.x = pkc(k0, k1); kv.y = pkc(k2, k3);
    *reinterpret_cast<uint2*>(Qb + ((size_t)b * NN + n) * 8 + 4 * h) = qv;
    *reinterpret_cast<uint2*>(Kb + ((size_t)b * NN + n) * 8 + 4 * h) = kv;
  }
}

// ---------------- Kernel B: double-buffered persistent flash ---------------
// 256 blocks (4b x 16qc x 4sp; sp XCD-constant) x 512 thr (8 waves x 32 q).
// 4 phases of 256 keys, DOUBLE-BUFFERED: STAGE(next) issued before
// COMPUTE(cur); the end-of-phase __syncthreads drains the prefetch after
// compute, so staging hides under MFMA/exp. Phase order rotated by qc&3
// (key order is free: no running max) to de-burst EA traffic.
// QK = one 32x32x16 MFMA (d=8 zero-padded); P in registers; PV = 4 MFMAs;
// l via ones-channel MFMA. LDS 72.3KB -> 2 blocks/CU, 4 waves/SIMD.
__global__ __launch_bounds__(512, 4) void flash_attn(
    const u16* __restrict__ Qb, const u16* __restrict__ Kb,
    const u16* __restrict__ Vb, u32* __restrict__ ACCu,
    float* __restrict__ Lb) {
  __shared__ u16 Klds[2][PHK * 8 + 8];     // [buf][256 keys * 8 d + 16B pad]
  __shared__ u16 Vlds[2][64 * VST];        // [buf][64 ch][256 keys] swizzled
  const int bid = blockIdx.x;
  const int sp = bid & 3;                  // XCD-constant
  const int rest = bid >> 2;               // 0..63
  const int qc = rest & 15;
  const int b = rest >> 4;
  const int w = __builtin_amdgcn_readfirstlane(threadIdx.x >> 6);
  const int lane = threadIdx.x & 63;
  const int l31 = lane & 31;
  const int h = lane >> 5;
  const int qrow0 = qc * 256 + w * 32;
  const int ks = sp * KLEN;
  const int rot = qc & 3;                  // phase rotation

  if (threadIdx.x < 8) {                   // zero pad for h1 K-frag reads
    Klds[0][PHK * 8 + threadIdx.x] = 0;
    Klds[1][PHK * 8 + threadIdx.x] = 0;
  }

  bf16x8 qf = {0, 0, 0, 0, 0, 0, 0, 0};
  if (h == 0)
    qf = *reinterpret_cast<const bf16x8*>(Qb + ((size_t)b * NN + qrow0 + l31) * 8);

  const u16* Kp = Kb + ((size_t)b * NN + ks) * 8;
  const u16* Vp = Vb + (size_t)b * CH * NN + ks;

  // per-lane staging geometry: instr i covers V rows 8w+2i (lanes 0-31) and
  // 8w+2i+1 (lanes 32-63); chunk (lane&31) pre-swizzled by m(ch)=(ch^(ch>>3))&7.
  size_t vsrc[4];
#pragma unroll
  for (int i = 0; i < 4; ++i) {
    const int ch = 8 * w + 2 * i + (lane >> 5);
    const int mm = (ch ^ (ch >> 3)) & 7;
    const int c = lane & 31;
    vsrc[i] = (size_t)ch * NN + (size_t)((((c & 24) | ((c ^ mm) & 7)) << 3));
  }

#define STAGE(php, bb) do {                                                   \
    const int kofs_ = (php) * PHK;                                            \
    _Pragma("unroll")                                                         \
    for (int i_ = 0; i_ < 4; ++i_)                                            \
      __builtin_amdgcn_global_load_lds(                                       \
          (const __attribute__((address_space(1))) void*)(Vp + vsrc[i_] + kofs_), \
          (__attribute__((address_space(3))) void*)&Vlds[bb][(8 * w + 2 * i_) * VST], 16, 0, 0); \
    if (w < 4)                                                                \
      __builtin_amdgcn_global_load_lds(                                       \
          (const __attribute__((address_space(1))) void*)(Kp + (size_t)(kofs_ + 64 * w + lane) * 8), \
          (__attribute__((address_space(3))) void*)&Klds[bb][64 * w * 8], 16, 0, 0); \
  } while (0)

  f32x16 acc0 = {}, acc1 = {}, acc2 = {};
  const f32x16 zz = {};
  const short one = (short)0x3F80;         // bf16 1.0
  const bf16x8 zero8 = {0, 0, 0, 0, 0, 0, 0, 0};
  const bf16x8 ones8 = {one, one, one, one, one, one, one, one};
  const bf16x8 af1 = (l31 == 0) ? ones8 : zero8;  // ones-channel A-frag
  const int m0 = (l31 ^ (l31 >> 3)) & 7;   // swizzle mask for ch = l31
  const int m1 = m0 ^ 4;                   // for ch = 32 + l31

  STAGE(rot, 0);
  __syncthreads();                         // buffer 0 ready
#pragma unroll
  for (int i = 0; i < NP; ++i) {
    const int bb = i & 1;
    if (i + 1 < NP) STAGE((rot + i + 1) & 3, bb ^ 1);   // prefetch next
#pragma unroll 4
    for (int kk = 0; kk < PHK / 32; ++kk) {
      // QK: A = K[32 keys][d] (h1 -> zero pad), B = Q^T (h1 -> zeros)
      const int kaddr = h ? PHK * 8 : (kk * 32 + l31) * 8;
      bf16x8 kf = *reinterpret_cast<const bf16x8*>(&Klds[bb][kaddr]);
      f32x16 s = __builtin_amdgcn_mfma_f32_32x32x16_bf16(kf, qf, zz, 0, 0, 0);
      // P = exp2(S); lane (q=l31, h) holds key perm-slots (r&3)+8*(r>>2)+4h
      float p[16];
#pragma unroll
      for (int r = 0; r < 16; ++r) p[r] = exp2f(s[r]);
      union { uint4 u; bf16x8 v; } pb0, pb1;
      pb0.u.x = pkc(p[0], p[1]);   pb0.u.y = pkc(p[2], p[3]);
      pb0.u.z = pkc(p[4], p[5]);   pb0.u.w = pkc(p[6], p[7]);
      pb1.u.x = pkc(p[8], p[9]);   pb1.u.y = pkc(p[10], p[11]);
      pb1.u.z = pkc(p[12], p[13]); pb1.u.w = pkc(p[14], p[15]);
      // PV: O^T[64ch][32q]; 16B chunk g deswizzled per-row (32 chunks/row)
      const int g0 = kk * 4 + h;
      const int g1 = g0 + 2;
      const int cp00 = (g0 & 24) | ((g0 ^ m0) & 7);
      const int cp01 = (g1 & 24) | ((g1 ^ m0) & 7);
      const int cp10 = (g0 & 24) | ((g0 ^ m1) & 7);
      const int cp11 = (g1 & 24) | ((g1 ^ m1) & 7);
      bf16x8 v00 = *reinterpret_cast<const bf16x8*>(&Vlds[bb][l31 * VST + cp00 * 8]);
      bf16x8 v01 = *reinterpret_cast<const bf16x8*>(&Vlds[bb][l31 * VST + cp01 * 8]);
      bf16x8 v10 = *reinterpret_cast<const bf16x8*>(&Vlds[bb][(32 + l31) * VST + cp10 * 8]);
      bf16x8 v11 = *reinterpret_cast<const bf16x8*>(&Vlds[bb][(32 + l31) * VST + cp11 * 8]);
      acc0 = __builtin_amdgcn_mfma_f32_32x32x16_bf16(v00, pb0.v, acc0, 0, 0, 0);
      acc0 = __builtin_amdgcn_mfma_f32_32x32x16_bf16(v01, pb1.v, acc0, 0, 0, 0);
      acc1 = __builtin_amdgcn_mfma_f32_32x32x16_bf16(v10, pb0.v, acc1, 0, 0, 0);
      acc1 = __builtin_amdgcn_mfma_f32_32x32x16_bf16(v11, pb1.v, acc1, 0, 0, 0);
      acc2 = __builtin_amdgcn_mfma_f32_32x32x16_bf16(af1, pb0.v, acc2, 0, 0, 0);
      acc2 = __builtin_amdgcn_mfma_f32_32x32x16_bf16(af1, pb1.v, acc2, 0, 0, 0);
    }
    __syncthreads();   // drains prefetch (vmcnt) + gates buffer reuse
  }
#undef STAGE

  // l(q) = acc2 row 0 (on h=0 lanes); replicate across h
  float lsum = acc2[0];
  lsum += __shfl_xor(lsum, 32);

  // partials: ACC as packed bf16 ch-pairs [gtile][sp][32 chpair][32 q]
  const int gtile = b * (NN / 32) + qc * 8 + w;
  u32* A = ACCu + ((size_t)gtile * SPLIT + sp) * 32 * 32;
#pragma unroll
  for (int rp = 0; rp < 8; ++rp) {
    const int chp = (rp & 1) + 4 * (rp >> 1) + 2 * h;   // = ch>>1, ch even
    __builtin_nontemporal_store(pkc(acc0[2 * rp], acc0[2 * rp + 1]),
                                &A[chp * 32 + l31]);
    __builtin_nontemporal_store(pkc(acc1[2 * rp], acc1[2 * rp + 1]),
                                &A[(16 + chp) * 32 + l31]);
  }
  if (h == 0)
    __builtin_nontemporal_store(lsum, &Lb[((size_t)gtile * SPLIT + sp) * 32 + l31]);
}

// ---------------- Kernel C: combine split partials + epilogue ---------------
// One thread -> 4 consecutive positions x 2 channels (vectorized).
__global__ __launch_bounds__(256) void combine(
    const float* __restrict__ x, const float* __restrict__ gamma,
    const u32* __restrict__ ACCu, const float* __restrict__ Lb,
    float* __restrict__ out) {
  const int idx = blockIdx.x * 256 + threadIdx.x;   // over NB*32*(NN/4)
  const int n4 = idx & (NN / 4 - 1);
  const int cp = (idx >> 10) & 31;
  const int b = idx >> 15;
  const int n = n4 << 2;
  const int gtile = b * (NN / 32) + (n >> 5);
  const int q0 = n & 31;                   // multiple of 4
  const uint4* A4 = reinterpret_cast<const uint4*>(ACCu);
  const float4* L4 = reinterpret_cast<const float4*>(Lb);
  float s0[4] = {0.f, 0.f, 0.f, 0.f}, s1[4] = {0.f, 0.f, 0.f, 0.f};
  float l[4] = {0.f, 0.f, 0.f, 0.f};
#pragma unroll
  for (int sp = 0; sp < SPLIT; ++sp) {
    const uint4 a = A4[(((size_t)gtile * SPLIT + sp) * 32 + cp) * 8 + (q0 >> 2)];
    const float4 lv = L4[(((size_t)gtile * SPLIT + sp) * 32 + q0) >> 2];
    const u32 av[4] = {a.x, a.y, a.z, a.w};
#pragma unroll
    for (int k = 0; k < 4; ++k) {
      union { u32 u; float f; } lo, hi;
      lo.u = av[k] << 16; hi.u = av[k] & 0xffff0000u;
      s0[k] += lo.f; s1[k] += hi.f;
    }
    l[0] += lv.x; l[1] += lv.y; l[2] += lv.z; l[3] += lv.w;
  }
  const float gm = gamma[0];
  float inv[4];
#pragma unroll
  for (int k = 0; k < 4; ++k) inv[k] = gm / l[k];
  const size_t i0 = ((size_t)b * CH + 2 * cp) * NN + n;
  const float4 x0 = *reinterpret_cast<const float4*>(x + i0);
  const float4 x1 = *reinterpret_cast<const float4*>(x + i0 + NN);
  float4 o0, o1;
  o0.x = fmaf(inv[0], s0[0], x0.x); o0.y = fmaf(inv[1], s0[1], x0.y);
  o0.z = fmaf(inv[2], s0[2], x0.z); o0.w = fmaf(inv[3], s0[3], x0.w);
  o1.x = fmaf(inv[0], s1[0], x1.x); o1.y = fmaf(inv[1], s1[1], x1.y);
  o1.z = fmaf(inv[2], s1[2], x1.z); o1.w = fmaf(inv[3], s1[3], x1.w);
  *reinterpret_cast<float4*>(out + i0) = o0;
  *reinterpret_cast<float4*>(out + i0 + NN) = o1;
}

extern "C" void kernel_launch(void* const* d_in, const int* in_sizes, int n_in,
                              void* d_out, int out_size, void* d_ws, size_t ws_size,
                              hipStream_t stream) {
  const float* x     = (const float*)d_in[0];
  const float* wq    = (const float*)d_in[1];
  const float* bq    = (const float*)d_in[2];
  const float* wk    = (const float*)d_in[3];
  const float* bk    = (const float*)d_in[4];
  const float* wv    = (const float*)d_in[5];
  const float* bv    = (const float*)d_in[6];
  const float* gamma = (const float*)d_in[7];
  float* out = (float*)d_out;

  // ws: Q 256KB | K 256KB | V 2MB | ACC(bf16 pairs) 8.4MB | L 256KB
  u16* Qb = (u16*)d_ws;
  u16* Kb = Qb + (size_t)NB * NN * 8;
  u16* Vb = Kb + (size_t)NB * NN * 8;
  u32* ACCu = (u32*)(Vb + (size_t)NB * CH * NN);
  float* Lb = (float*)(ACCu + (size_t)NB * (NN / 32) * SPLIT * 32 * 32);

  qkv_proj<<<dim3(NB * (NN / 32)), dim3(192), 0, stream>>>(
      x, wq, bq, wk, bk, wv, bv, Qb, Kb, Vb);
  flash_attn<<<dim3(NB * 16 * SPLIT), dim3(512), 0, stream>>>(
      Qb, Kb, Vb, ACCu, Lb);
  combine<<<dim3((NB * 32 * (NN / 4)) / 256), dim3(256), 0, stream>>>(
      x, gamma, ACCu, Lb, out);
}